// Round 1
// baseline (886.002 us; speedup 1.0000x reference)
//
#include <hip/hip_runtime.h>
#include <cstddef>

// ---------------------------------------------------------------------------
// CrystalGNN (SchNet-style) fused pipeline, all f32.
//   K0 embed:  x[n][j] = emb[x_ids[n]][j]
//   K1 rbf:    e[E][10] = exp(-1.125*(d - r*2/3)^2)
//   per conv layer l in 0..2:
//     memset agg
//     k_gemm64<0,0>: h = x @ W1[l] + b1[l]
//     k_edge:        f = e@We[l]+be[l]; m = h[src]*f; agg[dst] += m (atomic)
//     k_gemm64<1,1>: x = softplus(x + agg @ W2[l] + b2[l])
//   pool (atomic mean), head MLP (1 block / graph, wave0=bg wave1=eh)
// ---------------------------------------------------------------------------

__device__ __forceinline__ float softplusf(float v) {
    // stable: max(v,0) + log1p(exp(-|v|))
    return fmaxf(v, 0.0f) + log1pf(__expf(-fabsf(v)));
}

__device__ __forceinline__ void fatomic_add(float* p, float v) {
    unsafeAtomicAdd(p, v);   // global_atomic_add_f32, avoids CAS-loop lowering
}

__global__ void k_embed(const int* __restrict__ ids, const float* __restrict__ emb,
                        float* __restrict__ x, int n_nodes) {
    int idx = blockIdx.x * blockDim.x + threadIdx.x;
    if (idx >= n_nodes * 64) return;
    int n = idx >> 6, j = idx & 63;
    x[idx] = emb[ids[n] * 64 + j];
}

__global__ void k_rbf(const float* __restrict__ dist, float* __restrict__ e, int n_edges) {
    int idx = blockIdx.x * blockDim.x + threadIdx.x;
    if (idx >= n_edges * 10) return;
    int ei = idx / 10;
    int r = idx - ei * 10;
    float d = dist[ei];
    float t = d - (float)r * (6.0f / 9.0f);
    e[idx] = __expf(-1.125f * t * t);
}

// Y[n][j] = act( (ADD? addIn[n][j]:0) + bias[j] + sum_k X[n][k]*W[k][j] )
// wave per node, lane = output feature j; W column held in 64 VGPRs.
template <int ACT, int ADD>
__global__ void k_gemm64(const float* __restrict__ X, const float* __restrict__ W,
                         const float* __restrict__ bias, const float* __restrict__ addIn,
                         float* __restrict__ Y, int n_nodes) {
    int lane = threadIdx.x & 63;
    int gw = (blockIdx.x * blockDim.x + threadIdx.x) >> 6;
    gw = __builtin_amdgcn_readfirstlane(gw);
    int nw = (gridDim.x * blockDim.x) >> 6;

    float w[64];
#pragma unroll
    for (int k = 0; k < 64; ++k) w[k] = W[k * 64 + lane];
    float bj = bias[lane];

    for (int n = gw; n < n_nodes; n += nw) {
        const float4* xr = (const float4*)(X + (size_t)n * 64);
        float acc = bj;
#pragma unroll
        for (int q = 0; q < 16; ++q) {
            float4 xv = xr[q];  // wave-uniform address -> broadcast from L1
            acc = fmaf(xv.x, w[4 * q + 0], acc);
            acc = fmaf(xv.y, w[4 * q + 1], acc);
            acc = fmaf(xv.z, w[4 * q + 2], acc);
            acc = fmaf(xv.w, w[4 * q + 3], acc);
        }
        if (ADD) acc += addIn[(size_t)n * 64 + lane];
        if (ACT) acc = softplusf(acc);
        Y[(size_t)n * 64 + lane] = acc;
    }
}

// wave per edge, lane = feature. We column (10 regs) per lane.
__global__ void k_edge(const float* __restrict__ e, const float* __restrict__ h,
                       const int* __restrict__ src, const int* __restrict__ dst,
                       const float* __restrict__ We, const float* __restrict__ be,
                       float* __restrict__ agg, int n_edges) {
    int lane = threadIdx.x & 63;
    int gw = (blockIdx.x * blockDim.x + threadIdx.x) >> 6;
    gw = __builtin_amdgcn_readfirstlane(gw);
    int nw = (gridDim.x * blockDim.x) >> 6;

    float w[10];
#pragma unroll
    for (int r = 0; r < 10; ++r) w[r] = We[r * 64 + lane];
    float bj = be[lane];

    for (int ei = gw; ei < n_edges; ei += nw) {
        int s = __builtin_amdgcn_readfirstlane(src[ei]);
        int t = __builtin_amdgcn_readfirstlane(dst[ei]);
        const float* er = e + (size_t)ei * 10;
        float f = bj;
#pragma unroll
        for (int r = 0; r < 10; ++r) f = fmaf(er[r], w[r], f);
        float m = h[(size_t)s * 64 + lane] * f;
        fatomic_add(agg + (size_t)t * 64 + lane, m);
    }
}

__global__ void k_pool(const float* __restrict__ x, const int* __restrict__ batch,
                       float* __restrict__ sums, float* __restrict__ cnt, int n_nodes) {
    int idx = blockIdx.x * blockDim.x + threadIdx.x;
    if (idx >= n_nodes * 64) return;
    int n = idx >> 6, j = idx & 63;
    int b = batch[n];
    fatomic_add(sums + (size_t)b * 64 + j, x[idx]);
    if (j == 0) fatomic_add(cnt + b, 1.0f);
}

// one block (128 threads) per graph; wave 0 -> bg head, wave 1 -> eh head.
__global__ void k_head(const float* __restrict__ sums, const float* __restrict__ cnt,
                       const float* __restrict__ Ws, const float* __restrict__ bs,
                       const float* __restrict__ Wbg1, const float* __restrict__ bbg1,
                       const float* __restrict__ Wbg2, const float* __restrict__ bbg2,
                       const float* __restrict__ Weh1, const float* __restrict__ beh1,
                       const float* __restrict__ Weh2, const float* __restrict__ beh2,
                       float* __restrict__ out, int n_graphs) {
    __shared__ float c[64];
    __shared__ float h1[128];
    int g = blockIdx.x;
    int t = threadIdx.x;  // 0..127
    if (t < 64) {
        float cn = fmaxf(cnt[g], 1.0f);
        c[t] = sums[(size_t)g * 64 + t] / cn;
    }
    __syncthreads();
    float a = bs[t];
#pragma unroll 8
    for (int k = 0; k < 64; ++k) a = fmaf(c[k], Ws[k * 128 + t], a);
    h1[t] = fmaxf(a, 0.0f);
    __syncthreads();

    const float* W1p = (t < 64) ? Wbg1 : Weh1;
    const float* b1p = (t < 64) ? bbg1 : beh1;
    const float* W2p = (t < 64) ? Wbg2 : Weh2;
    float b2v = (t < 64) ? bbg2[0] : beh2[0];
    int lane = t & 63;
    float a2 = b1p[lane];
#pragma unroll 8
    for (int k = 0; k < 128; ++k) a2 = fmaf(h1[k], W1p[k * 64 + lane], a2);
    a2 = fmaxf(a2, 0.0f);
    float p = a2 * W2p[lane];
#pragma unroll
    for (int off = 32; off > 0; off >>= 1) p += __shfl_down(p, off);
    if (lane == 0) out[(t < 64 ? 0 : n_graphs) + g] = p + b2v;
}

extern "C" void kernel_launch(void* const* d_in, const int* in_sizes, int n_in,
                              void* d_out, int out_size, void* d_ws, size_t ws_size,
                              hipStream_t stream) {
    const int*   x_ids = (const int*)d_in[0];
    const int*   eidx  = (const int*)d_in[1];
    const float* eattr = (const float*)d_in[2];
    const int*   batch = (const int*)d_in[3];
    const float* emb   = (const float*)d_in[4];
    const float* W1    = (const float*)d_in[5];
    const float* b1    = (const float*)d_in[6];
    const float* We    = (const float*)d_in[7];
    const float* be    = (const float*)d_in[8];
    const float* W2    = (const float*)d_in[9];
    const float* b2    = (const float*)d_in[10];
    const float* Ws_   = (const float*)d_in[11];
    const float* bs_   = (const float*)d_in[12];
    const float* Wbg1  = (const float*)d_in[13];
    const float* bbg1  = (const float*)d_in[14];
    const float* Wbg2  = (const float*)d_in[15];
    const float* bbg2  = (const float*)d_in[16];
    const float* Weh1  = (const float*)d_in[17];
    const float* beh1  = (const float*)d_in[18];
    const float* Weh2  = (const float*)d_in[19];
    const float* beh2  = (const float*)d_in[20];

    int n_nodes  = in_sizes[0];
    int n_edges  = in_sizes[2];
    int n_graphs = out_size / 2;
    const int* src = eidx;
    const int* dst = eidx + n_edges;

    float* ws   = (float*)d_ws;
    float* e    = ws;                               // E*10
    float* x    = e + (size_t)n_edges * 10;         // N*64
    float* h    = x + (size_t)n_nodes * 64;         // N*64
    float* agg  = h + (size_t)n_nodes * 64;         // N*64
    float* sums = agg + (size_t)n_nodes * 64;       // G*64
    float* cnt  = sums + (size_t)n_graphs * 64;     // G

    float* out = (float*)d_out;

    k_embed<<<(n_nodes * 64 + 255) / 256, 256, 0, stream>>>(x_ids, emb, x, n_nodes);
    k_rbf<<<(n_edges * 10 + 255) / 256, 256, 0, stream>>>(eattr, e, n_edges);

    for (int l = 0; l < 3; ++l) {
        hipMemsetAsync(agg, 0, (size_t)n_nodes * 64 * sizeof(float), stream);
        k_gemm64<0, 0><<<2048, 256, 0, stream>>>(x, W1 + l * 64 * 64, b1 + l * 64,
                                                 nullptr, h, n_nodes);
        k_edge<<<8192, 256, 0, stream>>>(e, h, src, dst, We + l * 10 * 64, be + l * 64,
                                         agg, n_edges);
        k_gemm64<1, 1><<<2048, 256, 0, stream>>>(agg, W2 + l * 64 * 64, b2 + l * 64,
                                                 x, x, n_nodes);
    }

    hipMemsetAsync(sums, 0, ((size_t)n_graphs * 64 + n_graphs) * sizeof(float), stream);
    k_pool<<<(n_nodes * 64 + 255) / 256, 256, 0, stream>>>(x, batch, sums, cnt, n_nodes);
    k_head<<<n_graphs, 128, 0, stream>>>(sums, cnt, Ws_, bs_, Wbg1, bbg1, Wbg2, bbg2,
                                         Weh1, beh1, Weh2, beh2, out, n_graphs);
}

// Round 2
// 710.802 us; speedup vs baseline: 1.2465x; 1.2465x over previous
//
#include <hip/hip_runtime.h>
#include <cstddef>

// ---------------------------------------------------------------------------
// CrystalGNN (SchNet-style), all f32. R2: atomic-free aggregation.
//   sort edges by dst (hist -> scan -> scatter, per call):
//     e_sorted[E][10] (RBF rows in sorted order), src_sorted[E], off[N+1]
//   per conv layer:
//     k_gemm64: h = x @ W1[l] + b1[l]
//     k_conv:   wave per node: acc[lane] = sum_{edges of n} h[src][lane]*f
//               then x[n] = softplus(x[n] + acc @ W2[l] + b2[l])  (shfl reduce)
//   pool: contiguous per-graph ranges (batch is sorted) -> c = mean
//   head MLP: 1 block / graph, wave0=bg wave1=eh
// ---------------------------------------------------------------------------

#define RBF_STEP (6.0f / 9.0f)
#define RBF_COEF (-1.125f)

__device__ __forceinline__ float softplusf(float v) {
    return fmaxf(v, 0.0f) + log1pf(__expf(-fabsf(v)));
}

__global__ void k_embed(const int* __restrict__ ids, const float* __restrict__ emb,
                        float* __restrict__ x, int n_nodes) {
    int idx = blockIdx.x * blockDim.x + threadIdx.x;
    if (idx >= n_nodes * 64) return;
    int n = idx >> 6, j = idx & 63;
    x[idx] = emb[ids[n] * 64 + j];
}

// ---------------- edge sort by dst ----------------
__global__ void k_hist(const int* __restrict__ dst, int* __restrict__ deg, int n_edges) {
    int e = blockIdx.x * blockDim.x + threadIdx.x;
    if (e < n_edges) atomicAdd(&deg[dst[e]], 1);
}

__global__ void k_scan1(const int* __restrict__ deg, int* __restrict__ bsum, int n) {
    __shared__ int s[256];
    int i = blockIdx.x * 256 + threadIdx.x;
    s[threadIdx.x] = (i < n) ? deg[i] : 0;
    __syncthreads();
    for (int off = 128; off > 0; off >>= 1) {
        if (threadIdx.x < off) s[threadIdx.x] += s[threadIdx.x + off];
        __syncthreads();
    }
    if (threadIdx.x == 0) bsum[blockIdx.x] = s[0];
}

__global__ void k_scan2(int* __restrict__ bsum, int nb) {  // single block of 256
    __shared__ int s[256];
    int v = (threadIdx.x < nb) ? bsum[threadIdx.x] : 0;
    s[threadIdx.x] = v;
    __syncthreads();
    for (int off = 1; off < 256; off <<= 1) {
        int t = (threadIdx.x >= off) ? s[threadIdx.x - off] : 0;
        __syncthreads();
        s[threadIdx.x] += t;
        __syncthreads();
    }
    if (threadIdx.x < nb) bsum[threadIdx.x] = s[threadIdx.x] - v;  // exclusive
}

__global__ void k_scan3(const int* __restrict__ deg, const int* __restrict__ bsum,
                        int* __restrict__ off_, int* __restrict__ cursor, int n) {
    __shared__ int s[256];
    int i = blockIdx.x * 256 + threadIdx.x;
    int v = (i < n) ? deg[i] : 0;
    s[threadIdx.x] = v;
    __syncthreads();
    for (int off = 1; off < 256; off <<= 1) {
        int t = (threadIdx.x >= off) ? s[threadIdx.x - off] : 0;
        __syncthreads();
        s[threadIdx.x] += t;
        __syncthreads();
    }
    if (i < n) {
        int incl = bsum[blockIdx.x] + s[threadIdx.x];
        off_[i + 1] = incl;
        cursor[i] = incl - v;   // exclusive prefix = fill cursor
    }
    if (i == 0) off_[0] = 0;
}

// scatter edge -> sorted slot; materialize RBF row at sorted position
__global__ void k_scatter(const int* __restrict__ src, const int* __restrict__ dst,
                          const float* __restrict__ dist, int* __restrict__ cursor,
                          int* __restrict__ ssort, float* __restrict__ esort, int n_edges) {
    int e = blockIdx.x * blockDim.x + threadIdx.x;
    if (e >= n_edges) return;
    int t = dst[e];
    int pos = atomicAdd(&cursor[t], 1);
    ssort[pos] = src[e];
    float d = dist[e];
    float* er = esort + (size_t)pos * 10;
#pragma unroll
    for (int r = 0; r < 10; ++r) {
        float u = d - (float)r * RBF_STEP;
        er[r] = __expf(RBF_COEF * u * u);
    }
}

// ---------------- node GEMM: h = x @ W1 + b1 ----------------
__global__ void k_gemm64(const float* __restrict__ X, const float* __restrict__ W,
                         const float* __restrict__ bias, float* __restrict__ Y, int n_nodes) {
    int lane = threadIdx.x & 63;
    int gw = (blockIdx.x * blockDim.x + threadIdx.x) >> 6;
    gw = __builtin_amdgcn_readfirstlane(gw);
    int nw = (gridDim.x * blockDim.x) >> 6;

    float w[64];
#pragma unroll
    for (int k = 0; k < 64; ++k) w[k] = W[k * 64 + lane];
    float bj = bias[lane];

    for (int n = gw; n < n_nodes; n += nw) {
        const float4* xr = (const float4*)(X + (size_t)n * 64);
        float acc = bj;
#pragma unroll
        for (int q = 0; q < 16; ++q) {
            float4 xv = xr[q];
            acc = fmaf(xv.x, w[4 * q + 0], acc);
            acc = fmaf(xv.y, w[4 * q + 1], acc);
            acc = fmaf(xv.z, w[4 * q + 2], acc);
            acc = fmaf(xv.w, w[4 * q + 3], acc);
        }
        Y[(size_t)n * 64 + lane] = acc;
    }
}

// ---------------- fused aggregation + residual + W2 + softplus ----------------
__global__ void k_conv(const float* __restrict__ esort, const int* __restrict__ ssort,
                       const int* __restrict__ off, const float* __restrict__ h,
                       const float* __restrict__ We, const float* __restrict__ be,
                       const float* __restrict__ W2, const float* __restrict__ b2,
                       float* __restrict__ x, int n_nodes) {
    int lane = threadIdx.x & 63;
    int gw = (blockIdx.x * blockDim.x + threadIdx.x) >> 6;
    gw = __builtin_amdgcn_readfirstlane(gw);
    int nw = (gridDim.x * blockDim.x) >> 6;

    float we[10];
#pragma unroll
    for (int r = 0; r < 10; ++r) we[r] = We[r * 64 + lane];
    float bj = be[lane];
    float w2[64];
#pragma unroll
    for (int k = 0; k < 64; ++k) w2[k] = W2[k * 64 + lane];
    float b2j = b2[lane];

    for (int n = gw; n < n_nodes; n += nw) {
        int k0 = off[n], k1 = off[n + 1];
        float acc = 0.0f;
        for (int k = k0; k < k1; ++k) {
            int s = ssort[k];
            const float* er = esort + (size_t)k * 10;
            float f = bj;
#pragma unroll
            for (int r = 0; r < 10; ++r) f = fmaf(er[r], we[r], f);
            acc = fmaf(h[(size_t)s * 64 + lane], f, acc);
        }
        // o[lane] = x[n][lane] + b2[lane] + sum_k acc_k * W2[k][lane]
        float o = b2j + x[(size_t)n * 64 + lane];
#pragma unroll
        for (int k = 0; k < 64; ++k) o = fmaf(__shfl(acc, k), w2[k], o);
        x[(size_t)n * 64 + lane] = softplusf(o);
    }
}

// ---------------- pooling over contiguous (sorted-batch) ranges ----------------
__global__ void k_gstart(const int* __restrict__ batch, int* __restrict__ gstart,
                         int n_nodes, int n_graphs) {
    int n = blockIdx.x * blockDim.x + threadIdx.x;
    if (n >= n_nodes) return;
    int b = batch[n];
    int prev = (n == 0) ? -1 : batch[n - 1];
    for (int g = prev + 1; g <= b; ++g) gstart[g] = n;
    if (n == n_nodes - 1)
        for (int g = b + 1; g <= n_graphs; ++g) gstart[g] = n_nodes;
}

__global__ void k_pool2(const float* __restrict__ x, const int* __restrict__ gstart,
                        float* __restrict__ c, int n_graphs) {
    __shared__ float red[256];
    int g = blockIdx.x;
    int t = threadIdx.x, j = t & 63, part = t >> 6;
    int s0 = gstart[g], s1 = gstart[g + 1];
    float acc = 0.0f;
    for (int n = s0 + part; n < s1; n += 4) acc += x[(size_t)n * 64 + j];
    red[t] = acc;
    __syncthreads();
    if (part == 0) {
        float v = red[j] + red[64 + j] + red[128 + j] + red[192 + j];
        float cnt = (float)(s1 - s0);
        c[(size_t)g * 64 + j] = v / fmaxf(cnt, 1.0f);
    }
}

// ---------------- head MLP: 1 block / graph; wave0=bg, wave1=eh ----------------
__global__ void k_head(const float* __restrict__ cmean,
                       const float* __restrict__ Ws, const float* __restrict__ bs,
                       const float* __restrict__ Wbg1, const float* __restrict__ bbg1,
                       const float* __restrict__ Wbg2, const float* __restrict__ bbg2,
                       const float* __restrict__ Weh1, const float* __restrict__ beh1,
                       const float* __restrict__ Weh2, const float* __restrict__ beh2,
                       float* __restrict__ out, int n_graphs) {
    __shared__ float c[64];
    __shared__ float h1[128];
    int g = blockIdx.x;
    int t = threadIdx.x;  // 0..127
    if (t < 64) c[t] = cmean[(size_t)g * 64 + t];
    __syncthreads();
    float a = bs[t];
#pragma unroll 8
    for (int k = 0; k < 64; ++k) a = fmaf(c[k], Ws[k * 128 + t], a);
    h1[t] = fmaxf(a, 0.0f);
    __syncthreads();

    const float* W1p = (t < 64) ? Wbg1 : Weh1;
    const float* b1p = (t < 64) ? bbg1 : beh1;
    const float* W2p = (t < 64) ? Wbg2 : Weh2;
    float b2v = (t < 64) ? bbg2[0] : beh2[0];
    int lane = t & 63;
    float a2 = b1p[lane];
#pragma unroll 8
    for (int k = 0; k < 128; ++k) a2 = fmaf(h1[k], W1p[k * 64 + lane], a2);
    a2 = fmaxf(a2, 0.0f);
    float p = a2 * W2p[lane];
#pragma unroll
    for (int off = 32; off > 0; off >>= 1) p += __shfl_down(p, off);
    if (lane == 0) out[(t < 64 ? 0 : n_graphs) + g] = p + b2v;
}

extern "C" void kernel_launch(void* const* d_in, const int* in_sizes, int n_in,
                              void* d_out, int out_size, void* d_ws, size_t ws_size,
                              hipStream_t stream) {
    const int*   x_ids = (const int*)d_in[0];
    const int*   eidx  = (const int*)d_in[1];
    const float* eattr = (const float*)d_in[2];
    const int*   batch = (const int*)d_in[3];
    const float* emb   = (const float*)d_in[4];
    const float* W1    = (const float*)d_in[5];
    const float* b1    = (const float*)d_in[6];
    const float* We    = (const float*)d_in[7];
    const float* be    = (const float*)d_in[8];
    const float* W2    = (const float*)d_in[9];
    const float* b2    = (const float*)d_in[10];
    const float* Ws_   = (const float*)d_in[11];
    const float* bs_   = (const float*)d_in[12];
    const float* Wbg1  = (const float*)d_in[13];
    const float* bbg1  = (const float*)d_in[14];
    const float* Wbg2  = (const float*)d_in[15];
    const float* bbg2  = (const float*)d_in[16];
    const float* Weh1  = (const float*)d_in[17];
    const float* beh1  = (const float*)d_in[18];
    const float* Weh2  = (const float*)d_in[19];
    const float* beh2  = (const float*)d_in[20];

    int n_nodes  = in_sizes[0];
    int n_edges  = in_sizes[2];
    int n_graphs = out_size / 2;
    const int* src = eidx;
    const int* dst = eidx + n_edges;

    // ---- workspace layout ----
    char* p = (char*)d_ws;
    float* esort = (float*)p;            p += (size_t)n_edges * 10 * sizeof(float);
    float* x     = (float*)p;            p += (size_t)n_nodes * 64 * sizeof(float);
    float* h     = (float*)p;            p += (size_t)n_nodes * 64 * sizeof(float);
    float* cmean = (float*)p;            p += (size_t)n_graphs * 64 * sizeof(float);
    int* ssort   = (int*)p;              p += (size_t)n_edges * sizeof(int);
    int* deg     = (int*)p;              p += (size_t)n_nodes * sizeof(int);
    int* off_    = (int*)p;              p += (size_t)(n_nodes + 1) * sizeof(int);
    int* cursor  = (int*)p;              p += (size_t)n_nodes * sizeof(int);
    int* bsum    = (int*)p;              p += 256 * sizeof(int);
    int* gstart  = (int*)p;              p += (size_t)(n_graphs + 1) * sizeof(int);

    float* out = (float*)d_out;

    int nb = (n_nodes + 255) / 256;  // 196 <= 256

    hipMemsetAsync(deg, 0, (size_t)n_nodes * sizeof(int), stream);
    k_embed<<<(n_nodes * 64 + 255) / 256, 256, 0, stream>>>(x_ids, emb, x, n_nodes);
    k_hist<<<(n_edges + 255) / 256, 256, 0, stream>>>(dst, deg, n_edges);
    k_scan1<<<nb, 256, 0, stream>>>(deg, bsum, n_nodes);
    k_scan2<<<1, 256, 0, stream>>>(bsum, nb);
    k_scan3<<<nb, 256, 0, stream>>>(deg, bsum, off_, cursor, n_nodes);
    k_scatter<<<(n_edges + 255) / 256, 256, 0, stream>>>(src, dst, eattr, cursor,
                                                         ssort, esort, n_edges);
    k_gstart<<<(n_nodes + 255) / 256, 256, 0, stream>>>(batch, gstart, n_nodes, n_graphs);

    for (int l = 0; l < 3; ++l) {
        k_gemm64<<<2048, 256, 0, stream>>>(x, W1 + l * 64 * 64, b1 + l * 64, h, n_nodes);
        k_conv<<<4096, 256, 0, stream>>>(esort, ssort, off_, h,
                                         We + l * 10 * 64, be + l * 64,
                                         W2 + l * 64 * 64, b2 + l * 64, x, n_nodes);
    }

    k_pool2<<<n_graphs, 256, 0, stream>>>(x, gstart, cmean, n_graphs);
    k_head<<<n_graphs, 128, 0, stream>>>(cmean, Ws_, bs_, Wbg1, bbg1, Wbg2, bbg2,
                                         Weh1, beh1, Weh2, beh2, out, n_graphs);
}

// Round 3
// 509.872 us; speedup vs baseline: 1.7377x; 1.3941x over previous
//
#include <hip/hip_runtime.h>
#include <cstddef>

// ---------------------------------------------------------------------------
// CrystalGNN (SchNet-style), all f32. R3: pipelined gather conv.
//   sort edges by dst (hist -> scan -> scatter) once per call:
//     esort[E][12] (RBF rows, padded to 12 for float4 align), ssort[E], off[N+1]
//   per conv layer:
//     k_gemm64: h = x @ W1[l] + b1[l]
//     k_conv:   wave per node, 4-edge software pipeline:
//               issue 4 ssort loads -> 4 h-gathers in flight -> f from float4
//               RBF rows -> acc FMAs. Epilogue: x = softplus(x + acc@W2 + b2)
//               via shfl reduce, W2 streamed from L1 (no 64-reg array).
//   pool: contiguous per-graph ranges (batch sorted); head: 1 block/graph.
// ---------------------------------------------------------------------------

#define RBF_STEP (6.0f / 9.0f)
#define RBF_COEF (-1.125f)

__device__ __forceinline__ float softplusf(float v) {
    return fmaxf(v, 0.0f) + log1pf(__expf(-fabsf(v)));
}

__global__ void k_embed(const int* __restrict__ ids, const float* __restrict__ emb,
                        float* __restrict__ x, int n_nodes) {
    int idx = blockIdx.x * blockDim.x + threadIdx.x;
    if (idx >= n_nodes * 64) return;
    int n = idx >> 6, j = idx & 63;
    x[idx] = emb[ids[n] * 64 + j];
}

// ---------------- edge sort by dst ----------------
__global__ void k_hist(const int* __restrict__ dst, int* __restrict__ deg, int n_edges) {
    int e = blockIdx.x * blockDim.x + threadIdx.x;
    if (e < n_edges) atomicAdd(&deg[dst[e]], 1);
}

__global__ void k_scan1(const int* __restrict__ deg, int* __restrict__ bsum, int n) {
    __shared__ int s[256];
    int i = blockIdx.x * 256 + threadIdx.x;
    s[threadIdx.x] = (i < n) ? deg[i] : 0;
    __syncthreads();
    for (int off = 128; off > 0; off >>= 1) {
        if (threadIdx.x < off) s[threadIdx.x] += s[threadIdx.x + off];
        __syncthreads();
    }
    if (threadIdx.x == 0) bsum[blockIdx.x] = s[0];
}

__global__ void k_scan2(int* __restrict__ bsum, int nb) {  // single block of 256
    __shared__ int s[256];
    int v = (threadIdx.x < nb) ? bsum[threadIdx.x] : 0;
    s[threadIdx.x] = v;
    __syncthreads();
    for (int off = 1; off < 256; off <<= 1) {
        int t = (threadIdx.x >= off) ? s[threadIdx.x - off] : 0;
        __syncthreads();
        s[threadIdx.x] += t;
        __syncthreads();
    }
    if (threadIdx.x < nb) bsum[threadIdx.x] = s[threadIdx.x] - v;  // exclusive
}

__global__ void k_scan3(const int* __restrict__ deg, const int* __restrict__ bsum,
                        int* __restrict__ off_, int* __restrict__ cursor, int n) {
    __shared__ int s[256];
    int i = blockIdx.x * 256 + threadIdx.x;
    int v = (i < n) ? deg[i] : 0;
    s[threadIdx.x] = v;
    __syncthreads();
    for (int off = 1; off < 256; off <<= 1) {
        int t = (threadIdx.x >= off) ? s[threadIdx.x - off] : 0;
        __syncthreads();
        s[threadIdx.x] += t;
        __syncthreads();
    }
    if (i < n) {
        int incl = bsum[blockIdx.x] + s[threadIdx.x];
        off_[i + 1] = incl;
        cursor[i] = incl - v;   // exclusive prefix = fill cursor
    }
    if (i == 0) off_[0] = 0;
}

// scatter edge -> sorted slot; materialize padded RBF row at sorted position
__global__ void k_scatter(const int* __restrict__ src, const int* __restrict__ dst,
                          const float* __restrict__ dist, int* __restrict__ cursor,
                          int* __restrict__ ssort, float* __restrict__ esort, int n_edges) {
    int e = blockIdx.x * blockDim.x + threadIdx.x;
    if (e >= n_edges) return;
    int t = dst[e];
    int pos = atomicAdd(&cursor[t], 1);
    ssort[pos] = src[e];
    float d = dist[e];
    float r_[10];
#pragma unroll
    for (int r = 0; r < 10; ++r) {
        float u = d - (float)r * RBF_STEP;
        r_[r] = __expf(RBF_COEF * u * u);
    }
    float4* er = (float4*)(esort + (size_t)pos * 12);
    er[0] = make_float4(r_[0], r_[1], r_[2], r_[3]);
    er[1] = make_float4(r_[4], r_[5], r_[6], r_[7]);
    er[2] = make_float4(r_[8], r_[9], 0.0f, 0.0f);
}

// ---------------- node GEMM: h = x @ W1 + b1 ----------------
__global__ void k_gemm64(const float* __restrict__ X, const float* __restrict__ W,
                         const float* __restrict__ bias, float* __restrict__ Y, int n_nodes) {
    int lane = threadIdx.x & 63;
    int gw = (blockIdx.x * blockDim.x + threadIdx.x) >> 6;
    gw = __builtin_amdgcn_readfirstlane(gw);
    int nw = (gridDim.x * blockDim.x) >> 6;

    float w[64];
#pragma unroll
    for (int k = 0; k < 64; ++k) w[k] = W[k * 64 + lane];
    float bj = bias[lane];

    for (int n = gw; n < n_nodes; n += nw) {
        const float4* xr = (const float4*)(X + (size_t)n * 64);
        float acc = bj;
#pragma unroll
        for (int q = 0; q < 16; ++q) {
            float4 xv = xr[q];
            acc = fmaf(xv.x, w[4 * q + 0], acc);
            acc = fmaf(xv.y, w[4 * q + 1], acc);
            acc = fmaf(xv.z, w[4 * q + 2], acc);
            acc = fmaf(xv.w, w[4 * q + 3], acc);
        }
        Y[(size_t)n * 64 + lane] = acc;
    }
}

// per-edge filter dot from 3 float4s
__device__ __forceinline__ float filt(const float we[10], float bj,
                                      float4 a, float4 b, float4 c) {
    float f = bj;
    f = fmaf(a.x, we[0], f); f = fmaf(a.y, we[1], f);
    f = fmaf(a.z, we[2], f); f = fmaf(a.w, we[3], f);
    f = fmaf(b.x, we[4], f); f = fmaf(b.y, we[5], f);
    f = fmaf(b.z, we[6], f); f = fmaf(b.w, we[7], f);
    f = fmaf(c.x, we[8], f); f = fmaf(c.y, we[9], f);
    return f;
}

// ---------------- fused aggregation + residual + W2 + softplus ----------------
__global__ void k_conv(const float* __restrict__ esort, const int* __restrict__ ssort,
                       const int* __restrict__ off, const float* __restrict__ h,
                       const float* __restrict__ We, const float* __restrict__ be,
                       const float* __restrict__ W2, const float* __restrict__ b2,
                       float* __restrict__ x, int n_nodes) {
    int lane = threadIdx.x & 63;
    int gw = (blockIdx.x * blockDim.x + threadIdx.x) >> 6;
    gw = __builtin_amdgcn_readfirstlane(gw);
    int nw = (gridDim.x * blockDim.x) >> 6;

    float we[10];
#pragma unroll
    for (int r = 0; r < 10; ++r) we[r] = We[r * 64 + lane];
    float bj = be[lane];
    float b2j = b2[lane];

    for (int n = gw; n < n_nodes; n += nw) {
        int k0 = off[n], k1 = off[n + 1];
        float acc = 0.0f;
        int k = k0;
        // 4-edge software pipeline: 4 independent gathers in flight
        for (; k + 4 <= k1; k += 4) {
            int s0 = ssort[k + 0], s1 = ssort[k + 1];
            int s2 = ssort[k + 2], s3 = ssort[k + 3];
            float g0 = h[(size_t)s0 * 64 + lane];
            float g1 = h[(size_t)s1 * 64 + lane];
            float g2 = h[(size_t)s2 * 64 + lane];
            float g3 = h[(size_t)s3 * 64 + lane];
            const float4* e0 = (const float4*)(esort + (size_t)(k + 0) * 12);
            const float4* e1 = (const float4*)(esort + (size_t)(k + 1) * 12);
            const float4* e2 = (const float4*)(esort + (size_t)(k + 2) * 12);
            const float4* e3 = (const float4*)(esort + (size_t)(k + 3) * 12);
            float f0 = filt(we, bj, e0[0], e0[1], e0[2]);
            float f1 = filt(we, bj, e1[0], e1[1], e1[2]);
            float f2 = filt(we, bj, e2[0], e2[1], e2[2]);
            float f3 = filt(we, bj, e3[0], e3[1], e3[2]);
            acc = fmaf(g0, f0, acc);
            acc = fmaf(g1, f1, acc);
            acc = fmaf(g2, f2, acc);
            acc = fmaf(g3, f3, acc);
        }
        for (; k < k1; ++k) {
            int s = ssort[k];
            float g = h[(size_t)s * 64 + lane];
            const float4* e0 = (const float4*)(esort + (size_t)k * 12);
            acc = fmaf(g, filt(we, bj, e0[0], e0[1], e0[2]), acc);
        }
        // o[lane] = x[n][lane] + b2[lane] + sum_kk acc_kk * W2[kk][lane]
        float o = b2j + x[(size_t)n * 64 + lane];
#pragma unroll 8
        for (int kk = 0; kk < 64; ++kk)
            o = fmaf(__shfl(acc, kk), W2[kk * 64 + lane], o);
        x[(size_t)n * 64 + lane] = softplusf(o);
    }
}

// ---------------- pooling over contiguous (sorted-batch) ranges ----------------
__global__ void k_gstart(const int* __restrict__ batch, int* __restrict__ gstart,
                         int n_nodes, int n_graphs) {
    int n = blockIdx.x * blockDim.x + threadIdx.x;
    if (n >= n_nodes) return;
    int b = batch[n];
    int prev = (n == 0) ? -1 : batch[n - 1];
    for (int g = prev + 1; g <= b; ++g) gstart[g] = n;
    if (n == n_nodes - 1)
        for (int g = b + 1; g <= n_graphs; ++g) gstart[g] = n_nodes;
}

__global__ void k_pool2(const float* __restrict__ x, const int* __restrict__ gstart,
                        float* __restrict__ c, int n_graphs) {
    __shared__ float red[256];
    int g = blockIdx.x;
    int t = threadIdx.x, j = t & 63, part = t >> 6;
    int s0 = gstart[g], s1 = gstart[g + 1];
    float acc = 0.0f;
    for (int n = s0 + part; n < s1; n += 4) acc += x[(size_t)n * 64 + j];
    red[t] = acc;
    __syncthreads();
    if (part == 0) {
        float v = red[j] + red[64 + j] + red[128 + j] + red[192 + j];
        float cnt = (float)(s1 - s0);
        c[(size_t)g * 64 + j] = v / fmaxf(cnt, 1.0f);
    }
}

// ---------------- head MLP: 1 block / graph; wave0=bg, wave1=eh ----------------
__global__ void k_head(const float* __restrict__ cmean,
                       const float* __restrict__ Ws, const float* __restrict__ bs,
                       const float* __restrict__ Wbg1, const float* __restrict__ bbg1,
                       const float* __restrict__ Wbg2, const float* __restrict__ bbg2,
                       const float* __restrict__ Weh1, const float* __restrict__ beh1,
                       const float* __restrict__ Weh2, const float* __restrict__ beh2,
                       float* __restrict__ out, int n_graphs) {
    __shared__ float c[64];
    __shared__ float h1[128];
    int g = blockIdx.x;
    int t = threadIdx.x;  // 0..127
    if (t < 64) c[t] = cmean[(size_t)g * 64 + t];
    __syncthreads();
    float a = bs[t];
#pragma unroll 8
    for (int k = 0; k < 64; ++k) a = fmaf(c[k], Ws[k * 128 + t], a);
    h1[t] = fmaxf(a, 0.0f);
    __syncthreads();

    const float* W1p = (t < 64) ? Wbg1 : Weh1;
    const float* b1p = (t < 64) ? bbg1 : beh1;
    const float* W2p = (t < 64) ? Wbg2 : Weh2;
    float b2v = (t < 64) ? bbg2[0] : beh2[0];
    int lane = t & 63;
    float a2 = b1p[lane];
#pragma unroll 8
    for (int k = 0; k < 128; ++k) a2 = fmaf(h1[k], W1p[k * 64 + lane], a2);
    a2 = fmaxf(a2, 0.0f);
    float p = a2 * W2p[lane];
#pragma unroll
    for (int off = 32; off > 0; off >>= 1) p += __shfl_down(p, off);
    if (lane == 0) out[(t < 64 ? 0 : n_graphs) + g] = p + b2v;
}

extern "C" void kernel_launch(void* const* d_in, const int* in_sizes, int n_in,
                              void* d_out, int out_size, void* d_ws, size_t ws_size,
                              hipStream_t stream) {
    const int*   x_ids = (const int*)d_in[0];
    const int*   eidx  = (const int*)d_in[1];
    const float* eattr = (const float*)d_in[2];
    const int*   batch = (const int*)d_in[3];
    const float* emb   = (const float*)d_in[4];
    const float* W1    = (const float*)d_in[5];
    const float* b1    = (const float*)d_in[6];
    const float* We    = (const float*)d_in[7];
    const float* be    = (const float*)d_in[8];
    const float* W2    = (const float*)d_in[9];
    const float* b2    = (const float*)d_in[10];
    const float* Ws_   = (const float*)d_in[11];
    const float* bs_   = (const float*)d_in[12];
    const float* Wbg1  = (const float*)d_in[13];
    const float* bbg1  = (const float*)d_in[14];
    const float* Wbg2  = (const float*)d_in[15];
    const float* bbg2  = (const float*)d_in[16];
    const float* Weh1  = (const float*)d_in[17];
    const float* beh1  = (const float*)d_in[18];
    const float* Weh2  = (const float*)d_in[19];
    const float* beh2  = (const float*)d_in[20];

    int n_nodes  = in_sizes[0];
    int n_edges  = in_sizes[2];
    int n_graphs = out_size / 2;
    const int* src = eidx;
    const int* dst = eidx + n_edges;

    // ---- workspace layout ----
    char* p = (char*)d_ws;
    float* esort = (float*)p;            p += (size_t)n_edges * 12 * sizeof(float);
    float* x     = (float*)p;            p += (size_t)n_nodes * 64 * sizeof(float);
    float* h     = (float*)p;            p += (size_t)n_nodes * 64 * sizeof(float);
    float* cmean = (float*)p;            p += (size_t)n_graphs * 64 * sizeof(float);
    int* ssort   = (int*)p;              p += (size_t)n_edges * sizeof(int);
    int* deg     = (int*)p;              p += (size_t)n_nodes * sizeof(int);
    int* off_    = (int*)p;              p += (size_t)(n_nodes + 1) * sizeof(int);
    int* cursor  = (int*)p;              p += (size_t)n_nodes * sizeof(int);
    int* bsum    = (int*)p;              p += 256 * sizeof(int);
    int* gstart  = (int*)p;              p += (size_t)(n_graphs + 1) * sizeof(int);

    float* out = (float*)d_out;

    int nb = (n_nodes + 255) / 256;  // 196 <= 256

    hipMemsetAsync(deg, 0, (size_t)n_nodes * sizeof(int), stream);
    k_embed<<<(n_nodes * 64 + 255) / 256, 256, 0, stream>>>(x_ids, emb, x, n_nodes);
    k_hist<<<(n_edges + 255) / 256, 256, 0, stream>>>(dst, deg, n_edges);
    k_scan1<<<nb, 256, 0, stream>>>(deg, bsum, n_nodes);
    k_scan2<<<1, 256, 0, stream>>>(bsum, nb);
    k_scan3<<<nb, 256, 0, stream>>>(deg, bsum, off_, cursor, n_nodes);
    k_scatter<<<(n_edges + 255) / 256, 256, 0, stream>>>(src, dst, eattr, cursor,
                                                         ssort, esort, n_edges);
    k_gstart<<<(n_nodes + 255) / 256, 256, 0, stream>>>(batch, gstart, n_nodes, n_graphs);

    for (int l = 0; l < 3; ++l) {
        k_gemm64<<<2048, 256, 0, stream>>>(x, W1 + l * 64 * 64, b1 + l * 64, h, n_nodes);
        k_conv<<<4096, 256, 0, stream>>>(esort, ssort, off_, h,
                                         We + l * 10 * 64, be + l * 64,
                                         W2 + l * 64 * 64, b2 + l * 64, x, n_nodes);
    }

    k_pool2<<<n_graphs, 256, 0, stream>>>(x, gstart, cmean, n_graphs);
    k_head<<<n_graphs, 128, 0, stream>>>(cmean, Ws_, bs_, Wbg1, bbg1, Wbg2, bbg2,
                                         Weh1, beh1, Weh2, beh2, out, n_graphs);
}

// Round 4
// 452.456 us; speedup vs baseline: 1.9582x; 1.1269x over previous
//
#include <hip/hip_runtime.h>
#include <hip/hip_fp16.h>
#include <cstddef>

// ---------------------------------------------------------------------------
// CrystalGNN (SchNet-style). R4.
//   Edge sort by dst (hist->scan->scatter), payload = int2{src, d_bits} (8 B).
//   RBF never materialized: e_r = A*B^r*C_r with A=exp(-1.125 d^2),
//   B=exp(1.5 d), C_r=exp(-0.5 r^2) folded into filter weights ->
//   f = be + A*horner(B; we'*C). 2 v_exp + 10 FMA per edge.
//   h table stored fp16 (halves gather bytes; 6.4 MB vs 4 MB L2/XCD).
//   k_conv: wave per node, 8/4/1 gather pipeline, fused residual+W2+softplus.
//   gemm0 fuses embedding lookup (emb is 24 KB, L1-resident).
// ---------------------------------------------------------------------------

__device__ __forceinline__ float softplusf(float v) {
    return fmaxf(v, 0.0f) + log1pf(__expf(-fabsf(v)));
}

// C_r = exp(-0.5 r^2), r = 0..9
#define RBF_C0 1.0f
#define RBF_C1 0.60653065971f
#define RBF_C2 0.13533528324f
#define RBF_C3 0.011108996538f
#define RBF_C4 3.3546262790e-4f
#define RBF_C5 3.7266531720e-6f
#define RBF_C6 1.5229979745e-8f
#define RBF_C7 2.2897348457e-11f
#define RBF_C8 1.2664165549e-14f
#define RBF_C9 2.5767043600e-18f

// ---------------- edge sort by dst ----------------
__global__ void k_hist(const int* __restrict__ dst, int* __restrict__ deg, int n_edges) {
    int e = blockIdx.x * blockDim.x + threadIdx.x;
    if (e < n_edges) atomicAdd(&deg[dst[e]], 1);
}

__global__ void k_scan1(const int* __restrict__ deg, int* __restrict__ bsum, int n) {
    __shared__ int s[256];
    int i = blockIdx.x * 256 + threadIdx.x;
    s[threadIdx.x] = (i < n) ? deg[i] : 0;
    __syncthreads();
    for (int off = 128; off > 0; off >>= 1) {
        if (threadIdx.x < off) s[threadIdx.x] += s[threadIdx.x + off];
        __syncthreads();
    }
    if (threadIdx.x == 0) bsum[blockIdx.x] = s[0];
}

__global__ void k_scan2(int* __restrict__ bsum, int nb) {  // single block of 256
    __shared__ int s[256];
    int v = (threadIdx.x < nb) ? bsum[threadIdx.x] : 0;
    s[threadIdx.x] = v;
    __syncthreads();
    for (int off = 1; off < 256; off <<= 1) {
        int t = (threadIdx.x >= off) ? s[threadIdx.x - off] : 0;
        __syncthreads();
        s[threadIdx.x] += t;
        __syncthreads();
    }
    if (threadIdx.x < nb) bsum[threadIdx.x] = s[threadIdx.x] - v;  // exclusive
}

__global__ void k_scan3(const int* __restrict__ deg, const int* __restrict__ bsum,
                        int* __restrict__ off_, int* __restrict__ cursor, int n) {
    __shared__ int s[256];
    int i = blockIdx.x * 256 + threadIdx.x;
    int v = (i < n) ? deg[i] : 0;
    s[threadIdx.x] = v;
    __syncthreads();
    for (int off = 1; off < 256; off <<= 1) {
        int t = (threadIdx.x >= off) ? s[threadIdx.x - off] : 0;
        __syncthreads();
        s[threadIdx.x] += t;
        __syncthreads();
    }
    if (i < n) {
        int incl = bsum[blockIdx.x] + s[threadIdx.x];
        off_[i + 1] = incl;
        cursor[i] = incl - v;   // exclusive prefix = fill cursor
    }
    if (i == 0) off_[0] = 0;
}

// scatter edge -> sorted slot: 8 B payload {src, d_bits}
__global__ void k_scatter(const int* __restrict__ src, const int* __restrict__ dst,
                          const float* __restrict__ dist, int* __restrict__ cursor,
                          int2* __restrict__ psort, int n_edges) {
    int e = blockIdx.x * blockDim.x + threadIdx.x;
    if (e >= n_edges) return;
    int t = dst[e];
    int pos = atomicAdd(&cursor[t], 1);
    psort[pos] = make_int2(src[e], __float_as_int(dist[e]));
}

// ---------------- layer-0: fused embed + h-gemm ----------------
__global__ void k_gemm0(const int* __restrict__ ids, const float* __restrict__ emb,
                        const float* __restrict__ W, const float* __restrict__ bias,
                        float* __restrict__ x, __half* __restrict__ h, int n_nodes) {
    int lane = threadIdx.x & 63;
    int gw = (blockIdx.x * blockDim.x + threadIdx.x) >> 6;
    gw = __builtin_amdgcn_readfirstlane(gw);
    int nw = (gridDim.x * blockDim.x) >> 6;

    float w[64];
#pragma unroll
    for (int k = 0; k < 64; ++k) w[k] = W[k * 64 + lane];
    float bj = bias[lane];

    for (int n = gw; n < n_nodes; n += nw) {
        int id = __builtin_amdgcn_readfirstlane(ids[n]);
        const float4* xr = (const float4*)(emb + (size_t)id * 64);
        float a0 = bj, a1 = 0.f, a2 = 0.f, a3 = 0.f;
#pragma unroll
        for (int q = 0; q < 4; ++q) {
            float4 v0 = xr[4 * q + 0], v1 = xr[4 * q + 1];
            float4 v2 = xr[4 * q + 2], v3 = xr[4 * q + 3];
            a0 = fmaf(v0.x, w[16 * q + 0], a0);  a0 = fmaf(v0.y, w[16 * q + 1], a0);
            a0 = fmaf(v0.z, w[16 * q + 2], a0);  a0 = fmaf(v0.w, w[16 * q + 3], a0);
            a1 = fmaf(v1.x, w[16 * q + 4], a1);  a1 = fmaf(v1.y, w[16 * q + 5], a1);
            a1 = fmaf(v1.z, w[16 * q + 6], a1);  a1 = fmaf(v1.w, w[16 * q + 7], a1);
            a2 = fmaf(v2.x, w[16 * q + 8], a2);  a2 = fmaf(v2.y, w[16 * q + 9], a2);
            a2 = fmaf(v2.z, w[16 * q + 10], a2); a2 = fmaf(v2.w, w[16 * q + 11], a2);
            a3 = fmaf(v3.x, w[16 * q + 12], a3); a3 = fmaf(v3.y, w[16 * q + 13], a3);
            a3 = fmaf(v3.z, w[16 * q + 14], a3); a3 = fmaf(v3.w, w[16 * q + 15], a3);
        }
        x[(size_t)n * 64 + lane] = emb[(size_t)id * 64 + lane];
        h[(size_t)n * 64 + lane] = __float2half((a0 + a1) + (a2 + a3));
    }
}

// ---------------- layers 1..: h = x @ W1 + b1 (fp16 out) ----------------
__global__ void k_gemm64(const float* __restrict__ X, const float* __restrict__ W,
                         const float* __restrict__ bias, __half* __restrict__ Y, int n_nodes) {
    int lane = threadIdx.x & 63;
    int gw = (blockIdx.x * blockDim.x + threadIdx.x) >> 6;
    gw = __builtin_amdgcn_readfirstlane(gw);
    int nw = (gridDim.x * blockDim.x) >> 6;

    float w[64];
#pragma unroll
    for (int k = 0; k < 64; ++k) w[k] = W[k * 64 + lane];
    float bj = bias[lane];

    for (int n = gw; n < n_nodes; n += nw) {
        const float4* xr = (const float4*)(X + (size_t)n * 64);
        float a0 = bj, a1 = 0.f, a2 = 0.f, a3 = 0.f;
#pragma unroll
        for (int q = 0; q < 4; ++q) {
            float4 v0 = xr[4 * q + 0], v1 = xr[4 * q + 1];
            float4 v2 = xr[4 * q + 2], v3 = xr[4 * q + 3];
            a0 = fmaf(v0.x, w[16 * q + 0], a0);  a0 = fmaf(v0.y, w[16 * q + 1], a0);
            a0 = fmaf(v0.z, w[16 * q + 2], a0);  a0 = fmaf(v0.w, w[16 * q + 3], a0);
            a1 = fmaf(v1.x, w[16 * q + 4], a1);  a1 = fmaf(v1.y, w[16 * q + 5], a1);
            a1 = fmaf(v1.z, w[16 * q + 6], a1);  a1 = fmaf(v1.w, w[16 * q + 7], a1);
            a2 = fmaf(v2.x, w[16 * q + 8], a2);  a2 = fmaf(v2.y, w[16 * q + 9], a2);
            a2 = fmaf(v2.z, w[16 * q + 10], a2); a2 = fmaf(v2.w, w[16 * q + 11], a2);
            a3 = fmaf(v3.x, w[16 * q + 12], a3); a3 = fmaf(v3.y, w[16 * q + 13], a3);
            a3 = fmaf(v3.z, w[16 * q + 14], a3); a3 = fmaf(v3.w, w[16 * q + 15], a3);
        }
        Y[(size_t)n * 64 + lane] = __float2half((a0 + a1) + (a2 + a3));
    }
}

// filter value from distance d via Horner: f = bj + A * P(B), wp[] = C_r*We[r][lane]
__device__ __forceinline__ float filt_d(const float wp[10], float bj, float d) {
    float A = __expf(-1.125f * d * d);
    float B = __expf(1.5f * d);
    float P = wp[9];
    P = fmaf(B, P, wp[8]); P = fmaf(B, P, wp[7]); P = fmaf(B, P, wp[6]);
    P = fmaf(B, P, wp[5]); P = fmaf(B, P, wp[4]); P = fmaf(B, P, wp[3]);
    P = fmaf(B, P, wp[2]); P = fmaf(B, P, wp[1]); P = fmaf(B, P, wp[0]);
    return fmaf(A, P, bj);
}

// ---------------- fused aggregation + residual + W2 + softplus ----------------
__global__ void k_conv(const int2* __restrict__ psort, const int* __restrict__ off,
                       const __half* __restrict__ h,
                       const float* __restrict__ We, const float* __restrict__ be,
                       const float* __restrict__ W2, const float* __restrict__ b2,
                       float* __restrict__ x, int n_nodes) {
    int lane = threadIdx.x & 63;
    int gw = (blockIdx.x * blockDim.x + threadIdx.x) >> 6;
    gw = __builtin_amdgcn_readfirstlane(gw);
    int nw = (gridDim.x * blockDim.x) >> 6;

    const float C[10] = {RBF_C0, RBF_C1, RBF_C2, RBF_C3, RBF_C4,
                         RBF_C5, RBF_C6, RBF_C7, RBF_C8, RBF_C9};
    float wp[10];
#pragma unroll
    for (int r = 0; r < 10; ++r) wp[r] = We[r * 64 + lane] * C[r];
    float bj = be[lane];
    float b2j = b2[lane];

    for (int n = gw; n < n_nodes; n += nw) {
        int k0 = off[n], k1 = off[n + 1];
        float acc = 0.0f;
        int k = k0;
        for (; k + 8 <= k1; k += 8) {     // 8 gathers in flight
            int2 p0 = psort[k + 0], p1 = psort[k + 1], p2 = psort[k + 2], p3 = psort[k + 3];
            int2 p4 = psort[k + 4], p5 = psort[k + 5], p6 = psort[k + 6], p7 = psort[k + 7];
            float g0 = __half2float(h[(size_t)p0.x * 64 + lane]);
            float g1 = __half2float(h[(size_t)p1.x * 64 + lane]);
            float g2 = __half2float(h[(size_t)p2.x * 64 + lane]);
            float g3 = __half2float(h[(size_t)p3.x * 64 + lane]);
            float g4 = __half2float(h[(size_t)p4.x * 64 + lane]);
            float g5 = __half2float(h[(size_t)p5.x * 64 + lane]);
            float g6 = __half2float(h[(size_t)p6.x * 64 + lane]);
            float g7 = __half2float(h[(size_t)p7.x * 64 + lane]);
            acc = fmaf(g0, filt_d(wp, bj, __int_as_float(p0.y)), acc);
            acc = fmaf(g1, filt_d(wp, bj, __int_as_float(p1.y)), acc);
            acc = fmaf(g2, filt_d(wp, bj, __int_as_float(p2.y)), acc);
            acc = fmaf(g3, filt_d(wp, bj, __int_as_float(p3.y)), acc);
            acc = fmaf(g4, filt_d(wp, bj, __int_as_float(p4.y)), acc);
            acc = fmaf(g5, filt_d(wp, bj, __int_as_float(p5.y)), acc);
            acc = fmaf(g6, filt_d(wp, bj, __int_as_float(p6.y)), acc);
            acc = fmaf(g7, filt_d(wp, bj, __int_as_float(p7.y)), acc);
        }
        for (; k + 4 <= k1; k += 4) {
            int2 p0 = psort[k + 0], p1 = psort[k + 1], p2 = psort[k + 2], p3 = psort[k + 3];
            float g0 = __half2float(h[(size_t)p0.x * 64 + lane]);
            float g1 = __half2float(h[(size_t)p1.x * 64 + lane]);
            float g2 = __half2float(h[(size_t)p2.x * 64 + lane]);
            float g3 = __half2float(h[(size_t)p3.x * 64 + lane]);
            acc = fmaf(g0, filt_d(wp, bj, __int_as_float(p0.y)), acc);
            acc = fmaf(g1, filt_d(wp, bj, __int_as_float(p1.y)), acc);
            acc = fmaf(g2, filt_d(wp, bj, __int_as_float(p2.y)), acc);
            acc = fmaf(g3, filt_d(wp, bj, __int_as_float(p3.y)), acc);
        }
        for (; k < k1; ++k) {
            int2 p = psort[k];
            float g = __half2float(h[(size_t)p.x * 64 + lane]);
            acc = fmaf(g, filt_d(wp, bj, __int_as_float(p.y)), acc);
        }
        // o[lane] = x[n][lane] + b2[lane] + sum_kk acc_kk * W2[kk][lane]
        float o = b2j + x[(size_t)n * 64 + lane];
#pragma unroll 8
        for (int kk = 0; kk < 64; ++kk)
            o = fmaf(__shfl(acc, kk), W2[kk * 64 + lane], o);
        x[(size_t)n * 64 + lane] = softplusf(o);
    }
}

// ---------------- pooling over contiguous (sorted-batch) ranges ----------------
__global__ void k_gstart(const int* __restrict__ batch, int* __restrict__ gstart,
                         int n_nodes, int n_graphs) {
    int n = blockIdx.x * blockDim.x + threadIdx.x;
    if (n >= n_nodes) return;
    int b = batch[n];
    int prev = (n == 0) ? -1 : batch[n - 1];
    for (int g = prev + 1; g <= b; ++g) gstart[g] = n;
    if (n == n_nodes - 1)
        for (int g = b + 1; g <= n_graphs; ++g) gstart[g] = n_nodes;
}

__global__ void k_pool2(const float* __restrict__ x, const int* __restrict__ gstart,
                        float* __restrict__ c, int n_graphs) {
    __shared__ float red[256];
    int g = blockIdx.x;
    int t = threadIdx.x, j = t & 63, part = t >> 6;
    int s0 = gstart[g], s1 = gstart[g + 1];
    float acc = 0.0f;
    for (int n = s0 + part; n < s1; n += 4) acc += x[(size_t)n * 64 + j];
    red[t] = acc;
    __syncthreads();
    if (part == 0) {
        float v = red[j] + red[64 + j] + red[128 + j] + red[192 + j];
        float cnt = (float)(s1 - s0);
        c[(size_t)g * 64 + j] = v / fmaxf(cnt, 1.0f);
    }
}

// ---------------- head MLP: 1 block / graph; wave0=bg, wave1=eh ----------------
__global__ void k_head(const float* __restrict__ cmean,
                       const float* __restrict__ Ws, const float* __restrict__ bs,
                       const float* __restrict__ Wbg1, const float* __restrict__ bbg1,
                       const float* __restrict__ Wbg2, const float* __restrict__ bbg2,
                       const float* __restrict__ Weh1, const float* __restrict__ beh1,
                       const float* __restrict__ Weh2, const float* __restrict__ beh2,
                       float* __restrict__ out, int n_graphs) {
    __shared__ float c[64];
    __shared__ float h1[128];
    int g = blockIdx.x;
    int t = threadIdx.x;  // 0..127
    if (t < 64) c[t] = cmean[(size_t)g * 64 + t];
    __syncthreads();
    float a = bs[t];
#pragma unroll 8
    for (int k = 0; k < 64; ++k) a = fmaf(c[k], Ws[k * 128 + t], a);
    h1[t] = fmaxf(a, 0.0f);
    __syncthreads();

    const float* W1p = (t < 64) ? Wbg1 : Weh1;
    const float* b1p = (t < 64) ? bbg1 : beh1;
    const float* W2p = (t < 64) ? Wbg2 : Weh2;
    float b2v = (t < 64) ? bbg2[0] : beh2[0];
    int lane = t & 63;
    float a2 = b1p[lane];
#pragma unroll 8
    for (int k = 0; k < 128; ++k) a2 = fmaf(h1[k], W1p[k * 64 + lane], a2);
    a2 = fmaxf(a2, 0.0f);
    float p = a2 * W2p[lane];
#pragma unroll
    for (int off = 32; off > 0; off >>= 1) p += __shfl_down(p, off);
    if (lane == 0) out[(t < 64 ? 0 : n_graphs) + g] = p + b2v;
}

extern "C" void kernel_launch(void* const* d_in, const int* in_sizes, int n_in,
                              void* d_out, int out_size, void* d_ws, size_t ws_size,
                              hipStream_t stream) {
    const int*   x_ids = (const int*)d_in[0];
    const int*   eidx  = (const int*)d_in[1];
    const float* eattr = (const float*)d_in[2];
    const int*   batch = (const int*)d_in[3];
    const float* emb   = (const float*)d_in[4];
    const float* W1    = (const float*)d_in[5];
    const float* b1    = (const float*)d_in[6];
    const float* We    = (const float*)d_in[7];
    const float* be    = (const float*)d_in[8];
    const float* W2    = (const float*)d_in[9];
    const float* b2    = (const float*)d_in[10];
    const float* Ws_   = (const float*)d_in[11];
    const float* bs_   = (const float*)d_in[12];
    const float* Wbg1  = (const float*)d_in[13];
    const float* bbg1  = (const float*)d_in[14];
    const float* Wbg2  = (const float*)d_in[15];
    const float* bbg2  = (const float*)d_in[16];
    const float* Weh1  = (const float*)d_in[17];
    const float* beh1  = (const float*)d_in[18];
    const float* Weh2  = (const float*)d_in[19];
    const float* beh2  = (const float*)d_in[20];

    int n_nodes  = in_sizes[0];
    int n_edges  = in_sizes[2];
    int n_graphs = out_size / 2;
    const int* src = eidx;
    const int* dst = eidx + n_edges;

    // ---- workspace layout (keep 256 B alignment between arrays) ----
    char* p = (char*)d_ws;
    float* x     = (float*)p;            p += (size_t)n_nodes * 64 * sizeof(float);
    __half* h    = (__half*)p;           p += (size_t)n_nodes * 64 * sizeof(__half);
    float* cmean = (float*)p;            p += (size_t)n_graphs * 64 * sizeof(float);
    int2* psort  = (int2*)p;             p += (size_t)n_edges * sizeof(int2);
    int* deg     = (int*)p;              p += (size_t)n_nodes * sizeof(int);
    int* off_    = (int*)p;              p += (size_t)(n_nodes + 1) * sizeof(int);
    int* cursor  = (int*)p;              p += (size_t)n_nodes * sizeof(int);
    int* bsum    = (int*)p;              p += 256 * sizeof(int);
    int* gstart  = (int*)p;              p += (size_t)(n_graphs + 1) * sizeof(int);

    float* out = (float*)d_out;

    int nb = (n_nodes + 255) / 256;  // 196 <= 256

    hipMemsetAsync(deg, 0, (size_t)n_nodes * sizeof(int), stream);
    k_hist<<<(n_edges + 255) / 256, 256, 0, stream>>>(dst, deg, n_edges);
    k_scan1<<<nb, 256, 0, stream>>>(deg, bsum, n_nodes);
    k_scan2<<<1, 256, 0, stream>>>(bsum, nb);
    k_scan3<<<nb, 256, 0, stream>>>(deg, bsum, off_, cursor, n_nodes);
    k_scatter<<<(n_edges + 255) / 256, 256, 0, stream>>>(src, dst, eattr, cursor,
                                                         psort, n_edges);
    k_gstart<<<(n_nodes + 255) / 256, 256, 0, stream>>>(batch, gstart, n_nodes, n_graphs);

    k_gemm0<<<2048, 256, 0, stream>>>(x_ids, emb, W1, b1, x, h, n_nodes);
    for (int l = 0; l < 3; ++l) {
        if (l > 0)
            k_gemm64<<<2048, 256, 0, stream>>>(x, W1 + l * 64 * 64, b1 + l * 64, h, n_nodes);
        k_conv<<<4096, 256, 0, stream>>>(psort, off_, h,
                                         We + l * 10 * 64, be + l * 64,
                                         W2 + l * 64 * 64, b2 + l * 64, x, n_nodes);
    }

    k_pool2<<<n_graphs, 256, 0, stream>>>(x, gstart, cmean, n_graphs);
    k_head<<<n_graphs, 128, 0, stream>>>(cmean, Ws_, bs_, Wbg1, bbg1, Wbg2, bbg2,
                                         Weh1, beh1, Weh2, beh2, out, n_graphs);
}